// Round 5
// baseline (106.691 us; speedup 1.0000x reference)
//
#include <hip/hip_runtime.h>

// Static config (matches reference)
#define T_Q 8
#define H_Q 16
#define W_Q 16
#define HEADS 8
#define QDIM 64
#define QTOK (T_Q * H_Q * W_Q)   // 2048
#define KTOK 2048                 // T_K*H_K*W_K

typedef float f32x4 __attribute__((ext_vector_type(4)));

// One row per wave, fully barrier-free and LDS-free.
// VMEM issue order is the whole trick (vmcnt waits oldest-first):
//   1) 16 emb f32x4 loads (L1-resident)   -> consumed at vmcnt(8)
//   2) 8 NT stream loads (HBM)            -> consumed last, in order
// q row is wave-uniform -> scalar s_loads (lgkmcnt pipe, not vmcnt).
// The dot + shfl redistribution runs entirely under the stream loads'
// HBM flight; no vmcnt(0) drain anywhere in the kernel.
__global__ __launch_bounds__(256)
void relpos_fused_kernel(const float* __restrict__ query,   // [B*H*QTOK, QDIM]
                         const float* __restrict__ scores,  // [B*H*QTOK, KTOK]
                         const float* __restrict__ hemb,    // [31, QDIM]
                         const float* __restrict__ wemb,    // [31, QDIM]
                         const float* __restrict__ temb,    // [15, QDIM]
                         float* __restrict__ out)           // [B*H*QTOK, KTOK]
{
    const int tid  = threadIdx.x;
    const int wid  = tid >> 6;          // wave id 0..3
    const int lane = tid & 63;
    const int row  = __builtin_amdgcn_readfirstlane(blockIdx.x * 4 + wid);
    const int qtok = row & (QTOK - 1);
    const int t = (qtok >> 8) & 7;
    const int h = (qtok >> 4) & 15;
    const int w = qtok & 15;

    // Per-lane emb row: lanes 0..15 -> rel_h[hk=lane], 16..31 -> rel_w[wk=lane-16],
    // 32..39 -> rel_t[tk=lane-32], 40..63 -> clamped duplicates (unused).
    const float* emb;
    if (lane < 16) {
        emb = hemb + (size_t)(h - lane + 15) * QDIM;             // dist = h - hk + 15
    } else if (lane < 32) {
        emb = wemb + (size_t)(w - (lane - 16) + 15) * QDIM;      // dist = w - wk + 15
    } else {
        emb = temb + (size_t)(t - ((lane - 32) & 7) + 7) * QDIM; // dist = t - tk + 7
    }

    // ---- Phase 1: issue the 16 emb vector loads FIRST (oldest in vmcnt).
    f32x4 e[16];
    #pragma unroll
    for (int c = 0; c < 16; ++c)
        e[c] = *reinterpret_cast<const f32x4*>(emb + c * 4);
    __builtin_amdgcn_sched_barrier(0);   // pin: emb loads precede stream loads

    // ---- Phase 2: issue the 8 NT stream loads (youngest in vmcnt).
    const size_t base = (size_t)row * KTOK + lane * 4;
    f32x4 s[8];
    #pragma unroll
    for (int it = 0; it < 8; ++it)
        s[it] = __builtin_nontemporal_load(
            reinterpret_cast<const f32x4*>(scores + base + it * 256));
    __builtin_amdgcn_sched_barrier(0);   // pin: stream loads issued before dot waits

    // ---- Phase 3: dot product. q row via wave-uniform scalar loads (lgkmcnt).
    const float* qrow = query + (size_t)row * QDIM;
    float a0 = 0.f, a1 = 0.f, a2 = 0.f, a3 = 0.f;
    #pragma unroll
    for (int c = 0; c < 16; ++c) {
        a0 += qrow[c * 4 + 0] * e[c].x;
        a1 += qrow[c * 4 + 1] * e[c].y;
        a2 += qrow[c * 4 + 2] * e[c].z;
        a3 += qrow[c * 4 + 3] * e[c].w;
    }
    const float acc = (a0 + a1) + (a2 + a3);

    // ---- Phase 4: redistribute via wave shuffles (no LDS, no barrier).
    const float rh   = __shfl(acc, lane >> 2, 64);
    const int   wk0  = (lane & 3) * 4;
    const float add0 = rh + __shfl(acc, 16 + wk0 + 0, 64);
    const float add1 = rh + __shfl(acc, 16 + wk0 + 1, 64);
    const float add2 = rh + __shfl(acc, 16 + wk0 + 2, 64);
    const float add3 = rh + __shfl(acc, 16 + wk0 + 3, 64);
    float rt[8];
    #pragma unroll
    for (int it = 0; it < 8; ++it) rt[it] = __shfl(acc, 32 + it, 64);

    // ---- Phase 5: combine + NT stores as each stream load lands (in order).
    #pragma unroll
    for (int it = 0; it < 8; ++it) {
        f32x4 o;
        o.x = s[it].x + add0 + rt[it];
        o.y = s[it].y + add1 + rt[it];
        o.z = s[it].z + add2 + rt[it];
        o.w = s[it].w + add3 + rt[it];
        __builtin_nontemporal_store(o,
            reinterpret_cast<f32x4*>(out + base + it * 256));
    }
}

extern "C" void kernel_launch(void* const* d_in, const int* in_sizes, int n_in,
                              void* d_out, int out_size, void* d_ws, size_t ws_size,
                              hipStream_t stream) {
    const float* query  = (const float*)d_in[0];  // [2,8,2048,64]
    const float* scores = (const float*)d_in[1];  // [2,8,2048,2048]
    const float* hemb   = (const float*)d_in[2];  // [31,64]
    const float* wemb   = (const float*)d_in[3];  // [31,64]
    const float* temb   = (const float*)d_in[4];  // [15,64]
    float* out = (float*)d_out;

    const int B = in_sizes[0] / (HEADS * QTOK * QDIM);   // = 2
    const int rows = B * HEADS * QTOK;                    // 32768

    relpos_fused_kernel<<<rows / 4, 256, 0, stream>>>(query, scores, hemb, wemb, temb, out);
}